// Round 6
// baseline (143.364 us; speedup 1.0000x reference)
//
#include <hip/hip_runtime.h>
#include <math.h>

#define BB 8
#define TT 96
#define SS 192
#define DIN 512
#define DM 512
#define SCALE 2.885390082f   // 2/ln2

typedef short short8 __attribute__((ext_vector_type(8)));
typedef float f32x4 __attribute__((ext_vector_type(4)));

__device__ __forceinline__ unsigned short f2bf(float f) {   // RNE (epilogues)
    unsigned int u = __float_as_uint(f);
    unsigned int r = u + 0x7FFFu + ((u >> 16) & 1u);
    return (unsigned short)(r >> 16);
}
__device__ __forceinline__ float bf2f(unsigned short h) {
    return __uint_as_float(((unsigned int)h) << 16);
}
// truncating fp32 pair -> bf16x2 in one v_perm_b32
__device__ __forceinline__ unsigned pk2(float lo, float hi) {
    return __builtin_amdgcn_perm(__float_as_uint(hi), __float_as_uint(lo), 0x07060302u);
}
__device__ __forceinline__ short8 pack_bf8(float4 a, float4 b) {
    union { unsigned u[4]; short8 s; } r;
    r.u[0] = pk2(a.x, a.y); r.u[1] = pk2(a.z, a.w);
    r.u[2] = pk2(b.x, b.y); r.u[3] = pk2(b.z, b.w);
    return r.s;
}

// ---------------- proj: wq/uh MFMA tiles + Wout convert, one dispatch ------
// blocks [0,288): 1152 wave-tiles 32x32 (wq: 384, uh: 768), fp32 in, depth-2
// register pipeline, inline cvt. Epilogue writes bf16 scaled by 2/ln2.
// blocks [288,352): Wout fp32->bf16 (RNE), 8192 elems/block.
__global__ __launch_bounds__(256) void proj_gemm(
    const float* __restrict__ inputs, const float* __restrict__ mems,
    const float* __restrict__ Wq, const float* __restrict__ Wc,
    const float* __restrict__ bc, const float* __restrict__ Wout,
    unsigned short* __restrict__ wq_s, unsigned short* __restrict__ uh_s,
    unsigned short* __restrict__ Wout_bf)
{
    const int bid = blockIdx.x;
    if (bid >= 288) {
        int base = (bid - 288) * 8192 + threadIdx.x * 8;
        #pragma unroll
        for (int i = 0; i < 4; ++i) {
            int idx = base + i * 2048;
            float4 a = *(const float4*)(Wout + idx);
            float4 b = *(const float4*)(Wout + idx + 4);
            short8 o;
            o[0] = (short)f2bf(a.x); o[1] = (short)f2bf(a.y);
            o[2] = (short)f2bf(a.z); o[3] = (short)f2bf(a.w);
            o[4] = (short)f2bf(b.x); o[5] = (short)f2bf(b.y);
            o[6] = (short)f2bf(b.z); o[7] = (short)f2bf(b.w);
            *(short8*)(Wout_bf + idx) = o;
        }
        return;
    }

    const int lane = threadIdx.x & 63;
    const int gid = bid * 4 + (threadIdx.x >> 6);
    const float *A, *W, *bias; unsigned short* out;
    int m0, n0;
    if (gid < 384) {
        A = inputs; W = Wq; bias = nullptr; out = wq_s;
        m0 = (gid % 24) * 32; n0 = (gid / 24) * 32;
    } else {
        int g = gid - 384;
        A = mems; W = Wc; bias = bc; out = uh_s;
        m0 = (g % 48) * 32; n0 = (g / 48) * 32;
    }

    const int mrow = lane & 15, quad = lane >> 4;
    const float* ap0 = A + (size_t)(m0 + mrow) * DM + quad * 8;
    const float* ap1 = ap0 + 16 * DM;
    const float* bp0 = W + (size_t)(n0 + mrow) * DM + quad * 8;
    const float* bp1 = bp0 + 16 * DM;

    f32x4 c00 = {0,0,0,0}, c01 = {0,0,0,0}, c10 = {0,0,0,0}, c11 = {0,0,0,0};
    float4 buf[2][8];
    auto ld = [&](int slot, int ks) {
        const int o = ks * 32;
        buf[slot][0] = *(const float4*)(ap0 + o);
        buf[slot][1] = *(const float4*)(ap0 + o + 4);
        buf[slot][2] = *(const float4*)(ap1 + o);
        buf[slot][3] = *(const float4*)(ap1 + o + 4);
        buf[slot][4] = *(const float4*)(bp0 + o);
        buf[slot][5] = *(const float4*)(bp0 + o + 4);
        buf[slot][6] = *(const float4*)(bp1 + o);
        buf[slot][7] = *(const float4*)(bp1 + o + 4);
    };
    ld(0, 0); ld(1, 1);
    #pragma unroll
    for (int ks = 0; ks < 16; ++ks) {
        const int sl = ks & 1;
        short8 a0 = pack_bf8(buf[sl][0], buf[sl][1]);
        short8 a1 = pack_bf8(buf[sl][2], buf[sl][3]);
        short8 b0 = pack_bf8(buf[sl][4], buf[sl][5]);
        short8 b1 = pack_bf8(buf[sl][6], buf[sl][7]);
        if (ks + 2 < 16) ld(sl, ks + 2);
        c00 = __builtin_amdgcn_mfma_f32_16x16x32_bf16(a0, b0, c00, 0, 0, 0);
        c01 = __builtin_amdgcn_mfma_f32_16x16x32_bf16(a0, b1, c01, 0, 0, 0);
        c10 = __builtin_amdgcn_mfma_f32_16x16x32_bf16(a1, b0, c10, 0, 0, 0);
        c11 = __builtin_amdgcn_mfma_f32_16x16x32_bf16(a1, b1, c11, 0, 0, 0);
    }

    f32x4 accs[2][2] = {{c00, c01}, {c10, c11}};
    #pragma unroll
    for (int mi = 0; mi < 2; ++mi)
        #pragma unroll
        for (int ni = 0; ni < 2; ++ni) {
            int col = n0 + ni * 16 + mrow;
            float bv = bias ? bias[col] : 0.0f;
            #pragma unroll
            for (int rg = 0; rg < 4; ++rg) {
                int row = m0 + mi * 16 + quad * 4 + rg;  // col=lane&15, row=quad*4+rg
                out[(size_t)row * DM + col] = f2bf((accs[mi][ni][rg] + bv) * SCALE);
            }
        }
}

// ---------------- fused scores + softmax + context, 1 row/block ------------
__global__ __launch_bounds__(256) void attn_core(
    const unsigned short* __restrict__ wq,      // [768][512] bf16, pre-scaled
    const unsigned short* __restrict__ uh,      // [1536][512] bf16, pre-scaled
    const float* __restrict__ v,                // [512] fp32
    const float* __restrict__ mems,             // [1536][512] fp32
    const int* __restrict__ masks,              // [B]
    float* __restrict__ align_out,              // [768][192] fp32
    unsigned short* __restrict__ c_bf)          // [768][512] bf16
{
    __shared__ float s_al[SS];
    __shared__ float s_part[4][DM];
    __shared__ float s_inv_sh;
    const int row = blockIdx.x, b = row / TT;
    const int tid = threadIdx.x, lane = tid & 63, w = tid >> 6;
    const int len = masks[b];
    const int mgrp = lane & 15, ssub = lane >> 4;

    // per-lane slices (m = inner*128 + mgrp*8 + j): q pre-scaled, wv = -2v
    float qv[4][8], wv[4][8], vsum = 0.f;
    #pragma unroll
    for (int inner = 0; inner < 4; ++inner) {
        short8 q8 = *(const short8*)(wq + (size_t)row * DM + inner * 128 + mgrp * 8);
        float4 va = *(const float4*)(v + inner * 128 + mgrp * 8);
        float4 vb = *(const float4*)(v + inner * 128 + mgrp * 8 + 4);
        #pragma unroll
        for (int j = 0; j < 8; ++j) qv[inner][j] = bf2f((unsigned short)q8[j]);
        float vt[8] = {va.x, va.y, va.z, va.w, vb.x, vb.y, vb.z, vb.w};
        #pragma unroll
        for (int j = 0; j < 8; ++j) { vsum += vt[j]; wv[inner][j] = -2.f * vt[j]; }
    }

    // scores: wave w covers s in [w*48, w*48+48), 4 s per iter
    for (int it = 0; it < 12; ++it) {
        const int s = w * 48 + it * 4 + ssub;
        const unsigned short* up = uh + ((size_t)b * SS + s) * DM + mgrp * 8;
        short8 u[4];
        #pragma unroll
        for (int inner = 0; inner < 4; ++inner)
            u[inner] = *(const short8*)(up + inner * 128);
        float acc = vsum;   // sum v*tanh = sum v + sum (-2v)/(e+1)
        #pragma unroll
        for (int inner = 0; inner < 4; ++inner)
            #pragma unroll
            for (int j = 0; j < 8; ++j) {
                float x = qv[inner][j] + bf2f((unsigned short)u[inner][j]);
                float e = __builtin_amdgcn_exp2f(x);
                float r = __builtin_amdgcn_rcpf(e + 1.f);
                acc = fmaf(wv[inner][j], r, acc);
            }
        acc += __shfl_xor(acc, 1);
        acc += __shfl_xor(acc, 2);
        acc += __shfl_xor(acc, 4);
        acc += __shfl_xor(acc, 8);
        if (mgrp == 0) s_al[s] = (s < len) ? acc : -INFINITY;
    }
    __syncthreads();

    if (tid < 64) {
        float m = fmaxf(fmaxf(s_al[tid], s_al[tid + 64]), s_al[tid + 128]);
        #pragma unroll
        for (int off = 32; off; off >>= 1) m = fmaxf(m, __shfl_xor(m, off));
        float e0 = __builtin_amdgcn_exp2f((s_al[tid]       - m) * 1.44269504f);
        float e1 = __builtin_amdgcn_exp2f((s_al[tid + 64]  - m) * 1.44269504f);
        float e2 = __builtin_amdgcn_exp2f((s_al[tid + 128] - m) * 1.44269504f);
        s_al[tid] = e0; s_al[tid + 64] = e1; s_al[tid + 128] = e2;
        float sum = e0 + e1 + e2;
        #pragma unroll
        for (int off = 32; off; off >>= 1) sum += __shfl_xor(sum, off);
        if (tid == 0) s_inv_sh = 1.0f / sum;
    }
    __syncthreads();
    const float inv = s_inv_sh;
    if (tid < SS) align_out[(size_t)row * SS + tid] = s_al[tid] * inv;

    // context: wave w covers s in [w*48,+48), lane owns d = lane*8..+8 (fp32 mems)
    float ac[8] = {0,0,0,0,0,0,0,0};
    {
        const float* mb = mems + ((size_t)b * SS + w * 48) * DM + lane * 8;
        #pragma unroll 6
        for (int i = 0; i < 48; ++i) {
            float4 m0 = *(const float4*)(mb + (size_t)i * DM);
            float4 m1 = *(const float4*)(mb + (size_t)i * DM + 4);
            float p = s_al[w * 48 + i];
            ac[0] = fmaf(p, m0.x, ac[0]); ac[1] = fmaf(p, m0.y, ac[1]);
            ac[2] = fmaf(p, m0.z, ac[2]); ac[3] = fmaf(p, m0.w, ac[3]);
            ac[4] = fmaf(p, m1.x, ac[4]); ac[5] = fmaf(p, m1.y, ac[5]);
            ac[6] = fmaf(p, m1.z, ac[6]); ac[7] = fmaf(p, m1.w, ac[7]);
        }
        #pragma unroll
        for (int j = 0; j < 8; ++j) s_part[w][lane * 8 + j] = ac[j];
    }
    __syncthreads();

    const int d = tid * 2;
    float r0 = s_part[0][d]     + s_part[1][d]     + s_part[2][d]     + s_part[3][d];
    float r1 = s_part[0][d + 1] + s_part[1][d + 1] + s_part[2][d + 1] + s_part[3][d + 1];
    unsigned int pack = ((unsigned int)f2bf(r1 * inv) << 16) | (unsigned int)f2bf(r0 * inv);
    *(unsigned int*)(c_bf + (size_t)row * DM + d) = pack;
}

// ---------------- out: attn_h = [c, inputs] @ Wout^T + bout ----------------
// 768 waves of 16x32 tiles, depth-2 pipeline; A = c_bf (bf16) for k<512,
// inputs (fp32, inline cvt) for k>=512; W = Wout_bf.
__global__ __launch_bounds__(256) void out_gemm(
    const unsigned short* __restrict__ c_bf,
    const float* __restrict__ inputs,
    const unsigned short* __restrict__ Wout_bf,
    const float* __restrict__ bout,
    float* __restrict__ attn_h)
{
    const int lane = threadIdx.x & 63;
    const int gid = blockIdx.x * 4 + (threadIdx.x >> 6);   // [0,768)
    const int m0 = (gid % 48) * 16, n0 = (gid / 48) * 32;
    const int mrow = lane & 15, quad = lane >> 4;

    const unsigned short* cp = c_bf + (size_t)(m0 + mrow) * DM + quad * 8;
    const float* ip = inputs + (size_t)(m0 + mrow) * DM + quad * 8;
    const unsigned short* wp0 = Wout_bf + (size_t)(n0 + mrow) * 1024 + quad * 8;
    const unsigned short* wp1 = wp0 + 16 * 1024;

    f32x4 c0 = {0,0,0,0}, c1 = {0,0,0,0};
    short8 abf[2]; float4 af32[2][2]; short8 w0b[2], w1b[2];
    auto ld = [&](int slot, int ks) {
        if (ks < 16) {
            abf[slot] = *(const short8*)(cp + ks * 32);
        } else {
            af32[slot][0] = *(const float4*)(ip + (ks - 16) * 32);
            af32[slot][1] = *(const float4*)(ip + (ks - 16) * 32 + 4);
        }
        w0b[slot] = *(const short8*)(wp0 + ks * 32);
        w1b[slot] = *(const short8*)(wp1 + ks * 32);
    };
    ld(0, 0); ld(1, 1);
    #pragma unroll
    for (int ks = 0; ks < 32; ++ks) {
        const int sl = ks & 1;
        short8 a = (ks < 16) ? abf[sl] : pack_bf8(af32[sl][0], af32[sl][1]);
        short8 b0 = w0b[sl], b1 = w1b[sl];
        if (ks + 2 < 32) ld(sl, ks + 2);
        c0 = __builtin_amdgcn_mfma_f32_16x16x32_bf16(a, b0, c0, 0, 0, 0);
        c1 = __builtin_amdgcn_mfma_f32_16x16x32_bf16(a, b1, c1, 0, 0, 0);
    }

    f32x4 accs[2] = {c0, c1};
    #pragma unroll
    for (int ni = 0; ni < 2; ++ni) {
        int col = n0 + ni * 16 + mrow;
        float bv = bout[col];
        #pragma unroll
        for (int rg = 0; rg < 4; ++rg) {
            int row = m0 + quad * 4 + rg;
            attn_h[(size_t)row * DIN + col] = accs[ni][rg] + bv;
        }
    }
}

extern "C" void kernel_launch(void* const* d_in, const int* in_sizes, int n_in,
                              void* d_out, int out_size, void* d_ws, size_t ws_size,
                              hipStream_t stream) {
    (void)in_sizes; (void)n_in; (void)out_size; (void)ws_size;
    const float* inputs = (const float*)d_in[0];
    const float* mems   = (const float*)d_in[1];
    const int*   masks  = (const int*)  d_in[2];
    const float* Wq     = (const float*)d_in[3];
    const float* Wc     = (const float*)d_in[4];
    const float* bc     = (const float*)d_in[5];
    const float* v      = (const float*)d_in[6];
    const float* Wout   = (const float*)d_in[7];
    const float* bout   = (const float*)d_in[8];

    unsigned short* p = (unsigned short*)d_ws;
    unsigned short* wq_s    = p;  p += 393216;   // [768][512]  (scaled 2/ln2)
    unsigned short* uh_s    = p;  p += 786432;   // [1536][512] (scaled 2/ln2)
    unsigned short* Wout_bf = p;  p += 524288;   // [512][1024]
    unsigned short* c_bf    = p;  p += 393216;   // [768][512]

    float* attn_h    = (float*)d_out;                    // [768][512]
    float* align_out = attn_h + (size_t)BB * TT * DIN;   // [768][192]

    proj_gemm<<<352, 256, 0, stream>>>(inputs, mems, Wq, Wc, bc, Wout,
                                       wq_s, uh_s, Wout_bf);
    attn_core<<<BB * TT, 256, 0, stream>>>(wq_s, uh_s, v, mems, masks,
                                           align_out, c_bf);
    out_gemm<<<192, 256, 0, stream>>>(c_bf, inputs, Wout_bf, bout, attn_h);
}